// Round 2
// baseline (908.968 us; speedup 1.0000x reference)
//
#include <hip/hip_runtime.h>
#include <math.h>

#define NN 20000
#define EE 320000

// scales
#define INV_UV    0.04419417382415922f   // 1/sqrt(64*8)
#define INV_MULS  0.125f                 // 1/sqrt(64)
#define S_BASIS   0.35355339059327373f   // 1/sqrt(8)
#define S_HID     0.125f                 // 1/sqrt(64)
#define INV_SQ3   0.5773502691896258f
#define AGG_SCALE (0.25f * 0.08838834764831845f)  // inv_nn * inv_mid

__device__ __forceinline__ float sspf(float x) {
  // softplus(x) - log(2), stable
  return fmaxf(x, 0.0f) + log1pf(__expf(-fabsf(x))) - 0.69314718055994531f;
}

// ---------------------------------------------------------------------------
// K1: per-node prep. 32 nodes / block, 256 threads.
//   - self-connection sc_s/sc_v written directly to out
//   - linear1 s, v written to workspace (v in planar [n][c][64] layout)
// sc formulated as GEMM: X[n, u*8+v] = feat_u[n]*attr_v[n], W = Wsc flat (512,64)
// ---------------------------------------------------------------------------
__global__ __launch_bounds__(256) void k1_node_prep(
    const float* __restrict__ node_feat, const float* __restrict__ node_attr,
    const float* __restrict__ W1s, const float* __restrict__ W1v,
    const float* __restrict__ Wsc_s, const float* __restrict__ Wsc_v,
    float* __restrict__ out_, float* __restrict__ ws_s, float* __restrict__ ws_v)
{
  __shared__ float s0T[64][33];      // s0T[u][n]
  __shared__ float v0T[3][64][33];   // v0T[c][u][n]
  __shared__ float attrT[8][33];     // attrT[v][n]
  __shared__ float XT[64][36];       // XT[k][n], K-chunk of 64
  __shared__ float Wl[64][68];       // W chunk [k][w]

  const int t = threadIdx.x;
  const int n0 = blockIdx.x * 32;

  // stage node_feat transposed
  #pragma unroll
  for (int i = 0; i < 32; ++i) {
    int idx = t + i * 256;
    int n = idx >> 8, j = idx & 255;
    float val = node_feat[(size_t)(n0 + n) * 256 + j];
    if (j < 64) s0T[j][n] = val;
    else { int r = j - 64; v0T[r % 3][r / 3][n] = val; }
  }
  {
    int n = t >> 3, v = t & 7;
    attrT[v][n] = node_attr[(size_t)(n0 + n) * 8 + v];
  }
  __syncthreads();

  const int tn = t >> 4;   // 0..15 -> node pair
  const int tw = t & 15;   // 0..15 -> w quad

  // ---- self connection: 4 channels (s, vx, vy, vz) ----
  for (int ch = 0; ch < 4; ++ch) {
    const float (*S)[33] = (ch == 0) ? s0T : v0T[ch - 1];
    const float* Wg = (ch == 0) ? Wsc_s : Wsc_v;
    float acc[2][4] = {{0.f,0.f,0.f,0.f},{0.f,0.f,0.f,0.f}};
    for (int kc = 0; kc < 8; ++kc) {
      #pragma unroll
      for (int i = 0; i < 8; ++i) {
        int idx = t + i * 256;
        int kk = idx >> 5, n = idx & 31;
        XT[kk][n] = S[kc * 8 + (kk >> 3)][n] * attrT[kk & 7][n];
      }
      #pragma unroll
      for (int i = 0; i < 16; ++i) {
        int idx = t + i * 256;
        int kk = idx >> 6, w = idx & 63;
        Wl[kk][w] = Wg[(size_t)(kc * 64 + kk) * 64 + w];
      }
      __syncthreads();
      #pragma unroll 8
      for (int kk = 0; kk < 64; ++kk) {
        float a0 = XT[kk][tn * 2 + 0];
        float a1 = XT[kk][tn * 2 + 1];
        float b0 = Wl[kk][tw * 4 + 0];
        float b1 = Wl[kk][tw * 4 + 1];
        float b2 = Wl[kk][tw * 4 + 2];
        float b3 = Wl[kk][tw * 4 + 3];
        acc[0][0] = fmaf(a0, b0, acc[0][0]);
        acc[0][1] = fmaf(a0, b1, acc[0][1]);
        acc[0][2] = fmaf(a0, b2, acc[0][2]);
        acc[0][3] = fmaf(a0, b3, acc[0][3]);
        acc[1][0] = fmaf(a1, b0, acc[1][0]);
        acc[1][1] = fmaf(a1, b1, acc[1][1]);
        acc[1][2] = fmaf(a1, b2, acc[1][2]);
        acc[1][3] = fmaf(a1, b3, acc[1][3]);
      }
      __syncthreads();
    }
    #pragma unroll
    for (int i = 0; i < 2; ++i) {
      int n = n0 + tn * 2 + i;
      #pragma unroll
      for (int j = 0; j < 4; ++j) {
        int w = tw * 4 + j;
        float val = acc[i][j] * INV_UV;
        if (ch == 0) out_[(size_t)n * 256 + w] = val;
        else         out_[(size_t)n * 256 + 64 + w * 3 + (ch - 1)] = val;
      }
    }
  }

  // ---- linear1: s = s0 @ W1s / 8 ----
  {
    #pragma unroll
    for (int i = 0; i < 16; ++i) {
      int idx = t + i * 256;
      Wl[idx >> 6][idx & 63] = W1s[idx];
    }
    __syncthreads();
    float acc[2][4] = {{0.f,0.f,0.f,0.f},{0.f,0.f,0.f,0.f}};
    #pragma unroll 8
    for (int kk = 0; kk < 64; ++kk) {
      float a0 = s0T[kk][tn * 2 + 0];
      float a1 = s0T[kk][tn * 2 + 1];
      float b0 = Wl[kk][tw * 4 + 0];
      float b1 = Wl[kk][tw * 4 + 1];
      float b2 = Wl[kk][tw * 4 + 2];
      float b3 = Wl[kk][tw * 4 + 3];
      acc[0][0] = fmaf(a0, b0, acc[0][0]);
      acc[0][1] = fmaf(a0, b1, acc[0][1]);
      acc[0][2] = fmaf(a0, b2, acc[0][2]);
      acc[0][3] = fmaf(a0, b3, acc[0][3]);
      acc[1][0] = fmaf(a1, b0, acc[1][0]);
      acc[1][1] = fmaf(a1, b1, acc[1][1]);
      acc[1][2] = fmaf(a1, b2, acc[1][2]);
      acc[1][3] = fmaf(a1, b3, acc[1][3]);
    }
    #pragma unroll
    for (int i = 0; i < 2; ++i) {
      int n = n0 + tn * 2 + i;
      #pragma unroll
      for (int j = 0; j < 4; ++j)
        ws_s[(size_t)n * 64 + tw * 4 + j] = acc[i][j] * INV_MULS;
    }
    __syncthreads();
    #pragma unroll
    for (int i = 0; i < 16; ++i) {
      int idx = t + i * 256;
      Wl[idx >> 6][idx & 63] = W1v[idx];
    }
    __syncthreads();
    #pragma unroll 1
    for (int c = 0; c < 3; ++c) {
      float acc2[2][4] = {{0.f,0.f,0.f,0.f},{0.f,0.f,0.f,0.f}};
      #pragma unroll 8
      for (int kk = 0; kk < 64; ++kk) {
        float a0 = v0T[c][kk][tn * 2 + 0];
        float a1 = v0T[c][kk][tn * 2 + 1];
        float b0 = Wl[kk][tw * 4 + 0];
        float b1 = Wl[kk][tw * 4 + 1];
        float b2 = Wl[kk][tw * 4 + 2];
        float b3 = Wl[kk][tw * 4 + 3];
        acc2[0][0] = fmaf(a0, b0, acc2[0][0]);
        acc2[0][1] = fmaf(a0, b1, acc2[0][1]);
        acc2[0][2] = fmaf(a0, b2, acc2[0][2]);
        acc2[0][3] = fmaf(a0, b3, acc2[0][3]);
        acc2[1][0] = fmaf(a1, b0, acc2[1][0]);
        acc2[1][1] = fmaf(a1, b1, acc2[1][1]);
        acc2[1][2] = fmaf(a1, b2, acc2[1][2]);
        acc2[1][3] = fmaf(a1, b3, acc2[1][3]);
      }
      #pragma unroll
      for (int i = 0; i < 2; ++i) {
        int n = n0 + tn * 2 + i;
        #pragma unroll
        for (int j = 0; j < 4; ++j)
          ws_v[((size_t)n * 3 + c) * 64 + tw * 4 + j] = acc2[i][j] * INV_MULS;
      }
    }
  }
}

// ---------------------------------------------------------------------------
// K2: per-edge. 32 edges / block, 256 threads.
//   phase1: H = ssp(basis @ Wfc1 / sqrt8)   (LDS)
//   phase2: W = H @ Wfc2 / 8                (thread t owns output column t,
//            Wfc2 column register-resident -> FMA-bound)
//   phase3: tensor product + atomic scatter into agg buffers
// ---------------------------------------------------------------------------
__global__ __launch_bounds__(256) void k2_edge(
    const float* __restrict__ edge_sh, const float* __restrict__ edge_basis,
    const float* __restrict__ Wfc1, const float* __restrict__ Wfc2,
    const int* __restrict__ edge_idx,
    const float* __restrict__ ws_s, const float* __restrict__ ws_v,
    float* __restrict__ aggS, float* __restrict__ aggV)
{
  __shared__ float basis[32][8];
  __shared__ float wfc1[8][64];
  __shared__ float H[32][68];
  __shared__ float Wt[32][256];
  __shared__ float sh[32][4];
  __shared__ int   eidx[32][2];

  const int t = threadIdx.x;
  const int e0 = blockIdx.x * 32;

  {
    int e = t >> 3, b = t & 7;
    basis[e][b] = edge_basis[(size_t)(e0 + e) * 8 + b];
  }
  #pragma unroll
  for (int i = 0; i < 2; ++i) {
    int idx = t + i * 256;
    wfc1[idx >> 6][idx & 63] = Wfc1[idx] * S_BASIS;
  }
  if (t < 128) sh[t >> 2][t & 3] = edge_sh[(size_t)(e0 + (t >> 2)) * 4 + (t & 3)];
  if (t < 64)  eidx[t >> 1][t & 1] = edge_idx[(size_t)(e0 + (t >> 1)) * 2 + (t & 1)];
  __syncthreads();

  // phase 1: H
  #pragma unroll
  for (int i = 0; i < 8; ++i) {
    int idx = t + i * 256;
    int e = idx >> 6, j = idx & 63;
    float a = 0.f;
    #pragma unroll
    for (int b = 0; b < 8; ++b) a = fmaf(basis[e][b], wfc1[b][j], a);
    H[e][j] = sspf(a);
  }
  __syncthreads();

  // phase 2: W = H @ Wfc2 * S_HID ; thread t owns column t
  float wreg[64];
  #pragma unroll
  for (int k = 0; k < 64; ++k) wreg[k] = Wfc2[(size_t)k * 256 + t] * S_HID;
  #pragma unroll 1
  for (int e = 0; e < 32; ++e) {
    float a = 0.f;
    #pragma unroll
    for (int k = 0; k < 64; ++k) a = fmaf(H[e][k], wreg[k], a);
    Wt[e][t] = a;
  }
  __syncthreads();

  // phase 3: tensor product + scatter (wave per 8 edges, lane = mul channel u)
  const int wv = t >> 6, lane = t & 63;
  #pragma unroll 1
  for (int ei = 0; ei < 8; ++ei) {
    const int e = wv * 8 + ei;
    const int dst = eidx[e][0], src = eidx[e][1];
    const float q0 = sh[e][0], q1 = sh[e][1], q2 = sh[e][2], q3 = sh[e][3];
    const float xs  = ws_s[(size_t)src * 64 + lane];
    const float xv0 = ws_v[((size_t)src * 3 + 0) * 64 + lane];
    const float xv1 = ws_v[((size_t)src * 3 + 1) * 64 + lane];
    const float xv2 = ws_v[((size_t)src * 3 + 2) * 64 + lane];
    const float wA = Wt[e][lane],       wB = Wt[e][64 + lane];
    const float wC = Wt[e][128 + lane], wD = Wt[e][192 + lane];
    float* aS = aggS + (size_t)dst * 128;
    float* aV = aggV + (size_t)dst * 384;
    atomicAdd(aS + lane,       wA * xs * q0);
    atomicAdd(aS + 64 + lane,  wD * (xv0 * q1 + xv1 * q2 + xv2 * q3) * INV_SQ3);
    const float wBxs = wB * xs;
    atomicAdd(aV + lane,       wBxs * q1);
    atomicAdd(aV + 64 + lane,  wC * xv0 * q0);
    atomicAdd(aV + 128 + lane, wBxs * q2);
    atomicAdd(aV + 192 + lane, wC * xv1 * q0);
    atomicAdd(aV + 256 + lane, wBxs * q3);
    atomicAdd(aV + 320 + lane, wC * xv2 * q0);
  }
}

// ---------------------------------------------------------------------------
// K4: final linear. 4 nodes / block (1 wave each), lane = output w.
//   out = agg @ W2 * inv_nn*inv_mid + sc (sc already in out from K1)
// ---------------------------------------------------------------------------
__global__ __launch_bounds__(256) void k4_final(
    const float* __restrict__ aggS, const float* __restrict__ aggV,
    const float* __restrict__ W2s, const float* __restrict__ W2v,
    float* __restrict__ out_)
{
  __shared__ float wsh[128][64];
  __shared__ float ag[4][512];
  const int t = threadIdx.x;
  const int wv = t >> 6, lane = t & 63;
  const int n = blockIdx.x * 4 + wv;

  #pragma unroll
  for (int i = 0; i < 32; ++i) { int idx = t + i * 256; wsh[idx >> 6][idx & 63] = W2s[idx]; }
  #pragma unroll
  for (int i = 0; i < 2; ++i) ag[wv][i * 64 + lane] = aggS[(size_t)n * 128 + i * 64 + lane];
  #pragma unroll
  for (int i = 0; i < 6; ++i) ag[wv][128 + i * 64 + lane] = aggV[(size_t)n * 384 + i * 64 + lane];
  __syncthreads();

  {
    float acc = 0.f;
    #pragma unroll 16
    for (int m = 0; m < 128; ++m) acc = fmaf(ag[wv][m], wsh[m][lane], acc);
    out_[(size_t)n * 256 + lane] += acc * AGG_SCALE;
  }
  __syncthreads();
  #pragma unroll
  for (int i = 0; i < 32; ++i) { int idx = t + i * 256; wsh[idx >> 6][idx & 63] = W2v[idx]; }
  __syncthreads();
  #pragma unroll 1
  for (int c = 0; c < 3; ++c) {
    float acc = 0.f;
    #pragma unroll 16
    for (int m = 0; m < 128; ++m) acc = fmaf(ag[wv][128 + c * 128 + m], wsh[m][lane], acc);
    out_[(size_t)n * 256 + 64 + lane * 3 + c] += acc * AGG_SCALE;
  }
}

extern "C" void kernel_launch(void* const* d_in, const int* in_sizes, int n_in,
                              void* d_out, int out_size, void* d_ws, size_t ws_size,
                              hipStream_t stream) {
  const float* node_feat  = (const float*)d_in[0];
  const float* node_attr  = (const float*)d_in[1];
  const float* edge_sh    = (const float*)d_in[2];
  const float* edge_basis = (const float*)d_in[3];
  const float* W1s        = (const float*)d_in[4];
  const float* W1v        = (const float*)d_in[5];
  const float* Wfc1       = (const float*)d_in[6];
  const float* Wfc2       = (const float*)d_in[7];
  const float* W2s        = (const float*)d_in[8];
  const float* W2v        = (const float*)d_in[9];
  const float* Wsc_s      = (const float*)d_in[10];
  const float* Wsc_v      = (const float*)d_in[11];
  const int*   edge_idx   = (const int*)d_in[12];
  float* out = (float*)d_out;

  char* ws = (char*)d_ws;
  float* ws_s = (float*)ws;                                  // N*64
  float* ws_v = (float*)(ws + (size_t)NN * 64 * 4);          // N*192
  float* aggS = (float*)(ws + (size_t)NN * 256 * 4);         // N*128
  float* aggV = (float*)(ws + (size_t)NN * 384 * 4);         // N*384
  // zero aggregation buffers (aggS and aggV are contiguous)
  hipMemsetAsync(aggS, 0, (size_t)NN * 512 * sizeof(float), stream);

  k1_node_prep<<<NN / 32, 256, 0, stream>>>(node_feat, node_attr, W1s, W1v,
                                            Wsc_s, Wsc_v, out, ws_s, ws_v);
  k2_edge<<<EE / 32, 256, 0, stream>>>(edge_sh, edge_basis, Wfc1, Wfc2, edge_idx,
                                       ws_s, ws_v, aggS, aggV);
  k4_final<<<NN / 4, 256, 0, stream>>>(aggS, aggV, W2s, W2v, out);
}

// Round 3
// 634.855 us; speedup vs baseline: 1.4318x; 1.4318x over previous
//
#include <hip/hip_runtime.h>
#include <math.h>

#define NN 20000
#define EE 320000

// scales
#define INV_UV    0.04419417382415922f   // 1/sqrt(64*8)
#define INV_MULS  0.125f                 // 1/sqrt(64)
#define S_BASIS   0.35355339059327373f   // 1/sqrt(8)
#define S_HID     0.125f                 // 1/sqrt(64)
#define INV_SQ3   0.5773502691896258f
#define AGG_SCALE (0.25f * 0.08838834764831845f)  // inv_nn * inv_mid

__device__ __forceinline__ float sspf(float x) {
  // softplus(x) - log(2), stable; v_log/v_exp based (threshold has big headroom)
  return fmaxf(x, 0.0f) + __logf(1.0f + __expf(-fabsf(x))) - 0.69314718055994531f;
}

// ---------------------------------------------------------------------------
// CSR build: histogram -> single-block scan -> scatter
// ---------------------------------------------------------------------------
__global__ __launch_bounds__(256) void k_hist(const int* __restrict__ edge_idx,
                                              int* __restrict__ deg) {
  int e = blockIdx.x * 256 + threadIdx.x;   // grid exact: EE/256
  atomicAdd(&deg[edge_idx[2 * (size_t)e]], 1);
}

__global__ __launch_bounds__(1024) void k_scan(const int* __restrict__ deg,
                                               int* __restrict__ cursor) {
  __shared__ int part[1024];
  const int t = threadIdx.x;
  const int base = t * 20;                  // 1024*20 = 20480 >= NN
  int loc[20];
  int run = 0;
  #pragma unroll
  for (int i = 0; i < 20; ++i) {
    int idx = base + i;
    int v = (idx < NN) ? deg[idx] : 0;
    loc[i] = run; run += v;
  }
  part[t] = run;
  __syncthreads();
  for (int off = 1; off < 1024; off <<= 1) {
    int v = (t >= off) ? part[t - off] : 0;
    __syncthreads();
    part[t] += v;
    __syncthreads();
  }
  int ex = (t > 0) ? part[t - 1] : 0;
  #pragma unroll
  for (int i = 0; i < 20; ++i) {
    int idx = base + i;
    if (idx < NN) cursor[idx] = ex + loc[i];
  }
}

__global__ __launch_bounds__(256) void k_scatter(const int* __restrict__ edge_idx,
                                                 int* __restrict__ cursor,
                                                 int* __restrict__ csr) {
  int e = blockIdx.x * 256 + threadIdx.x;   // grid exact: EE/256
  int dst = edge_idx[2 * (size_t)e];
  int pos = atomicAdd(&cursor[dst], 1);
  csr[pos] = e;
}

// ---------------------------------------------------------------------------
// K1: per-node prep (unchanged; measured ~76% of fp32 peak).
// ---------------------------------------------------------------------------
__global__ __launch_bounds__(256) void k1_node_prep(
    const float* __restrict__ node_feat, const float* __restrict__ node_attr,
    const float* __restrict__ W1s, const float* __restrict__ W1v,
    const float* __restrict__ Wsc_s, const float* __restrict__ Wsc_v,
    float* __restrict__ out_, float* __restrict__ ws_s, float* __restrict__ ws_v)
{
  __shared__ float s0T[64][33];
  __shared__ float v0T[3][64][33];
  __shared__ float attrT[8][33];
  __shared__ float XT[64][36];
  __shared__ float Wl[64][68];

  const int t = threadIdx.x;
  const int n0 = blockIdx.x * 32;

  #pragma unroll
  for (int i = 0; i < 32; ++i) {
    int idx = t + i * 256;
    int n = idx >> 8, j = idx & 255;
    float val = node_feat[(size_t)(n0 + n) * 256 + j];
    if (j < 64) s0T[j][n] = val;
    else { int r = j - 64; v0T[r % 3][r / 3][n] = val; }
  }
  {
    int n = t >> 3, v = t & 7;
    attrT[v][n] = node_attr[(size_t)(n0 + n) * 8 + v];
  }
  __syncthreads();

  const int tn = t >> 4;
  const int tw = t & 15;

  for (int ch = 0; ch < 4; ++ch) {
    const float (*S)[33] = (ch == 0) ? s0T : v0T[ch - 1];
    const float* Wg = (ch == 0) ? Wsc_s : Wsc_v;
    float acc[2][4] = {{0.f,0.f,0.f,0.f},{0.f,0.f,0.f,0.f}};
    for (int kc = 0; kc < 8; ++kc) {
      #pragma unroll
      for (int i = 0; i < 8; ++i) {
        int idx = t + i * 256;
        int kk = idx >> 5, n = idx & 31;
        XT[kk][n] = S[kc * 8 + (kk >> 3)][n] * attrT[kk & 7][n];
      }
      #pragma unroll
      for (int i = 0; i < 16; ++i) {
        int idx = t + i * 256;
        int kk = idx >> 6, w = idx & 63;
        Wl[kk][w] = Wg[(size_t)(kc * 64 + kk) * 64 + w];
      }
      __syncthreads();
      #pragma unroll 8
      for (int kk = 0; kk < 64; ++kk) {
        float a0 = XT[kk][tn * 2 + 0];
        float a1 = XT[kk][tn * 2 + 1];
        float b0 = Wl[kk][tw * 4 + 0];
        float b1 = Wl[kk][tw * 4 + 1];
        float b2 = Wl[kk][tw * 4 + 2];
        float b3 = Wl[kk][tw * 4 + 3];
        acc[0][0] = fmaf(a0, b0, acc[0][0]);
        acc[0][1] = fmaf(a0, b1, acc[0][1]);
        acc[0][2] = fmaf(a0, b2, acc[0][2]);
        acc[0][3] = fmaf(a0, b3, acc[0][3]);
        acc[1][0] = fmaf(a1, b0, acc[1][0]);
        acc[1][1] = fmaf(a1, b1, acc[1][1]);
        acc[1][2] = fmaf(a1, b2, acc[1][2]);
        acc[1][3] = fmaf(a1, b3, acc[1][3]);
      }
      __syncthreads();
    }
    #pragma unroll
    for (int i = 0; i < 2; ++i) {
      int n = n0 + tn * 2 + i;
      #pragma unroll
      for (int j = 0; j < 4; ++j) {
        int w = tw * 4 + j;
        float val = acc[i][j] * INV_UV;
        if (ch == 0) out_[(size_t)n * 256 + w] = val;
        else         out_[(size_t)n * 256 + 64 + w * 3 + (ch - 1)] = val;
      }
    }
  }

  {
    #pragma unroll
    for (int i = 0; i < 16; ++i) {
      int idx = t + i * 256;
      Wl[idx >> 6][idx & 63] = W1s[idx];
    }
    __syncthreads();
    float acc[2][4] = {{0.f,0.f,0.f,0.f},{0.f,0.f,0.f,0.f}};
    #pragma unroll 8
    for (int kk = 0; kk < 64; ++kk) {
      float a0 = s0T[kk][tn * 2 + 0];
      float a1 = s0T[kk][tn * 2 + 1];
      float b0 = Wl[kk][tw * 4 + 0];
      float b1 = Wl[kk][tw * 4 + 1];
      float b2 = Wl[kk][tw * 4 + 2];
      float b3 = Wl[kk][tw * 4 + 3];
      acc[0][0] = fmaf(a0, b0, acc[0][0]);
      acc[0][1] = fmaf(a0, b1, acc[0][1]);
      acc[0][2] = fmaf(a0, b2, acc[0][2]);
      acc[0][3] = fmaf(a0, b3, acc[0][3]);
      acc[1][0] = fmaf(a1, b0, acc[1][0]);
      acc[1][1] = fmaf(a1, b1, acc[1][1]);
      acc[1][2] = fmaf(a1, b2, acc[1][2]);
      acc[1][3] = fmaf(a1, b3, acc[1][3]);
    }
    #pragma unroll
    for (int i = 0; i < 2; ++i) {
      int n = n0 + tn * 2 + i;
      #pragma unroll
      for (int j = 0; j < 4; ++j)
        ws_s[(size_t)n * 64 + tw * 4 + j] = acc[i][j] * INV_MULS;
    }
    __syncthreads();
    #pragma unroll
    for (int i = 0; i < 16; ++i) {
      int idx = t + i * 256;
      Wl[idx >> 6][idx & 63] = W1v[idx];
    }
    __syncthreads();
    #pragma unroll 1
    for (int c = 0; c < 3; ++c) {
      float acc2[2][4] = {{0.f,0.f,0.f,0.f},{0.f,0.f,0.f,0.f}};
      #pragma unroll 8
      for (int kk = 0; kk < 64; ++kk) {
        float a0 = v0T[c][kk][tn * 2 + 0];
        float a1 = v0T[c][kk][tn * 2 + 1];
        float b0 = Wl[kk][tw * 4 + 0];
        float b1 = Wl[kk][tw * 4 + 1];
        float b2 = Wl[kk][tw * 4 + 2];
        float b3 = Wl[kk][tw * 4 + 3];
        acc2[0][0] = fmaf(a0, b0, acc2[0][0]);
        acc2[0][1] = fmaf(a0, b1, acc2[0][1]);
        acc2[0][2] = fmaf(a0, b2, acc2[0][2]);
        acc2[0][3] = fmaf(a0, b3, acc2[0][3]);
        acc2[1][0] = fmaf(a1, b0, acc2[1][0]);
        acc2[1][1] = fmaf(a1, b1, acc2[1][1]);
        acc2[1][2] = fmaf(a1, b2, acc2[1][2]);
        acc2[1][3] = fmaf(a1, b3, acc2[1][3]);
      }
      #pragma unroll
      for (int i = 0; i < 2; ++i) {
        int n = n0 + tn * 2 + i;
        #pragma unroll
        for (int j = 0; j < 4; ++j)
          ws_v[((size_t)n * 3 + c) * 64 + tw * 4 + j] = acc2[i][j] * INV_MULS;
      }
    }
  }
}

// ---------------------------------------------------------------------------
// K2 (CSR): 32 dst-sorted edges / block, 256 threads = 4 waves.
//   wave `part` owns W-part (0=A,1=B,2=C,3=D); lane = mul channel u.
//   Per edge: w = H[e]·Wfc2col (wreg registers), TP term accumulated in
//   REGISTERS; flushed with global atomicAdd only when dst changes.
// ---------------------------------------------------------------------------
__global__ __launch_bounds__(256) void k2_edge_csr(
    const float* __restrict__ edge_sh, const float* __restrict__ edge_basis,
    const float* __restrict__ Wfc1, const float* __restrict__ Wfc2,
    const int* __restrict__ edge_idx, const int* __restrict__ csr,
    const float* __restrict__ ws_s, const float* __restrict__ ws_v,
    float* __restrict__ aggS, float* __restrict__ aggV)
{
  __shared__ float basisL[32][8];
  __shared__ float wfc1[8][64];
  __shared__ float Hl[32][64];
  __shared__ float shL[32][4];
  __shared__ int   srcL[32];
  __shared__ int   dstL[32];

  const int t = threadIdx.x;
  const int e0 = blockIdx.x * 32;

  // stage basis (redundant csr reads hit L1) + per-edge meta
  {
    int eb = csr[e0 + (t >> 3)];
    basisL[t >> 3][t & 7] = edge_basis[(size_t)eb * 8 + (t & 7)];
  }
  if (t < 32) {
    int eid = csr[e0 + t];
    int2 di = *(const int2*)(edge_idx + 2 * (size_t)eid);
    dstL[t] = di.x; srcL[t] = di.y;
    float4 s4 = *(const float4*)(edge_sh + 4 * (size_t)eid);
    shL[t][0] = s4.x; shL[t][1] = s4.y; shL[t][2] = s4.z; shL[t][3] = s4.w;
  }
  #pragma unroll
  for (int i = 0; i < 2; ++i) {
    int idx = t + i * 256;
    wfc1[idx >> 6][idx & 63] = Wfc1[idx] * S_BASIS;
  }
  // Wfc2 column -> registers (global load, no LDS dependency)
  float wreg[64];
  #pragma unroll
  for (int k = 0; k < 64; ++k) wreg[k] = Wfc2[(size_t)k * 256 + t] * S_HID;
  __syncthreads();

  // H = ssp(basis @ Wfc1 * S_BASIS); one wave per row per iteration
  #pragma unroll
  for (int i = 0; i < 8; ++i) {
    int idx = t + i * 256;
    int e = idx >> 6, j = idx & 63;
    float a = 0.f;
    #pragma unroll
    for (int b = 0; b < 8; ++b) a = fmaf(basisL[e][b], wfc1[b][j], a);
    Hl[e][j] = sspf(a);
  }
  __syncthreads();

  const int part = t >> 6, lane = t & 63;
  float acc0 = 0.f, acc1 = 0.f, acc2 = 0.f;
  int cur = dstL[0];

  auto flush = [&](int node) {
    size_t nb = (size_t)node;
    if (part == 0)      atomicAdd(&aggS[nb * 128 + lane], acc0);
    else if (part == 3) atomicAdd(&aggS[nb * 128 + 64 + lane], acc0);
    else if (part == 1) {
      atomicAdd(&aggV[nb * 384 +       lane], acc0);
      atomicAdd(&aggV[nb * 384 + 128 + lane], acc1);
      atomicAdd(&aggV[nb * 384 + 256 + lane], acc2);
    } else {
      atomicAdd(&aggV[nb * 384 +  64 + lane], acc0);
      atomicAdd(&aggV[nb * 384 + 192 + lane], acc1);
      atomicAdd(&aggV[nb * 384 + 320 + lane], acc2);
    }
  };

  #pragma unroll 2
  for (int e = 0; e < 32; ++e) {
    const int dstE = dstL[e];        // wave-uniform
    if (dstE != cur) {
      flush(cur);
      acc0 = acc1 = acc2 = 0.f;
      cur = dstE;
    }
    const int srcE = srcL[e];
    // issue gathers early (latency hidden under the 64-FMA dot)
    float xs = 0.f, xv0 = 0.f, xv1 = 0.f, xv2 = 0.f;
    if (part <= 1) {
      xs = ws_s[(size_t)srcE * 64 + lane];
    } else {
      xv0 = ws_v[((size_t)srcE * 3 + 0) * 64 + lane];
      xv1 = ws_v[((size_t)srcE * 3 + 1) * 64 + lane];
      xv2 = ws_v[((size_t)srcE * 3 + 2) * 64 + lane];
    }
    const float q0 = shL[e][0], q1 = shL[e][1], q2 = shL[e][2], q3 = shL[e][3];
    // w = H[e] . wfc2col (LDS broadcast b128 reads + register weights)
    float w = 0.f;
    const float* Hr = &Hl[e][0];
    #pragma unroll
    for (int k4 = 0; k4 < 16; ++k4) {
      const float4 h = *(const float4*)(Hr + k4 * 4);
      w = fmaf(h.x, wreg[k4 * 4 + 0], w);
      w = fmaf(h.y, wreg[k4 * 4 + 1], w);
      w = fmaf(h.z, wreg[k4 * 4 + 2], w);
      w = fmaf(h.w, wreg[k4 * 4 + 3], w);
    }
    if (part == 0) {
      acc0 = fmaf(w * xs, q0, acc0);
    } else if (part == 1) {
      float wx = w * xs;
      acc0 = fmaf(wx, q1, acc0);
      acc1 = fmaf(wx, q2, acc1);
      acc2 = fmaf(wx, q3, acc2);
    } else if (part == 2) {
      float wq = w * q0;
      acc0 = fmaf(wq, xv0, acc0);
      acc1 = fmaf(wq, xv1, acc1);
      acc2 = fmaf(wq, xv2, acc2);
    } else {
      float d = xv0 * q1 + xv1 * q2 + xv2 * q3;
      acc0 = fmaf(w * INV_SQ3, d, acc0);
    }
  }
  flush(cur);
}

// ---------------------------------------------------------------------------
// K4: final linear as micro-tiled GEMM, 32 nodes / block, 2x4 register tile.
// ---------------------------------------------------------------------------
__global__ __launch_bounds__(256) void k4_final(
    const float* __restrict__ aggS, const float* __restrict__ aggV,
    const float* __restrict__ W2s, const float* __restrict__ W2v,
    float* __restrict__ out_)
{
  __shared__ float XT[128][33];   // 16.9 KB
  __shared__ float Wl[128][68];   // 34.8 KB
  const int t = threadIdx.x;
  const int n0 = blockIdx.x * 32;
  const int tn = t >> 4, tw = t & 15;

  // ---- scalar channel ----
  #pragma unroll
  for (int i = 0; i < 32; ++i) { int idx = t + i * 256; Wl[idx >> 6][idx & 63] = W2s[idx]; }
  #pragma unroll
  for (int i = 0; i < 16; ++i) {
    int idx = t + i * 256;
    int n = idx >> 7, k = idx & 127;
    XT[k][n] = aggS[(size_t)(n0 + n) * 128 + k];
  }
  __syncthreads();
  float acc[2][4] = {{0.f,0.f,0.f,0.f},{0.f,0.f,0.f,0.f}};
  #pragma unroll 8
  for (int kk = 0; kk < 128; ++kk) {
    float a0 = XT[kk][tn * 2 + 0], a1 = XT[kk][tn * 2 + 1];
    float b0 = Wl[kk][tw * 4 + 0], b1 = Wl[kk][tw * 4 + 1];
    float b2 = Wl[kk][tw * 4 + 2], b3 = Wl[kk][tw * 4 + 3];
    acc[0][0] = fmaf(a0, b0, acc[0][0]);
    acc[0][1] = fmaf(a0, b1, acc[0][1]);
    acc[0][2] = fmaf(a0, b2, acc[0][2]);
    acc[0][3] = fmaf(a0, b3, acc[0][3]);
    acc[1][0] = fmaf(a1, b0, acc[1][0]);
    acc[1][1] = fmaf(a1, b1, acc[1][1]);
    acc[1][2] = fmaf(a1, b2, acc[1][2]);
    acc[1][3] = fmaf(a1, b3, acc[1][3]);
  }
  #pragma unroll
  for (int i = 0; i < 2; ++i)
    #pragma unroll
    for (int j = 0; j < 4; ++j)
      out_[(size_t)(n0 + tn * 2 + i) * 256 + tw * 4 + j] += acc[i][j] * AGG_SCALE;

  // ---- vector channels (shared W2v) ----
  __syncthreads();
  #pragma unroll
  for (int i = 0; i < 32; ++i) { int idx = t + i * 256; Wl[idx >> 6][idx & 63] = W2v[idx]; }
  float accv[3][2][4];
  #pragma unroll
  for (int c = 0; c < 3; ++c) {
    __syncthreads();
    #pragma unroll
    for (int i = 0; i < 16; ++i) {
      int idx = t + i * 256;
      int n = idx >> 7, k = idx & 127;
      XT[k][n] = aggV[(size_t)(n0 + n) * 384 + c * 128 + k];
    }
    __syncthreads();
    #pragma unroll
    for (int i = 0; i < 2; ++i)
      #pragma unroll
      for (int j = 0; j < 4; ++j) accv[c][i][j] = 0.f;
    #pragma unroll 8
    for (int kk = 0; kk < 128; ++kk) {
      float a0 = XT[kk][tn * 2 + 0], a1 = XT[kk][tn * 2 + 1];
      float b0 = Wl[kk][tw * 4 + 0], b1 = Wl[kk][tw * 4 + 1];
      float b2 = Wl[kk][tw * 4 + 2], b3 = Wl[kk][tw * 4 + 3];
      accv[c][0][0] = fmaf(a0, b0, accv[c][0][0]);
      accv[c][0][1] = fmaf(a0, b1, accv[c][0][1]);
      accv[c][0][2] = fmaf(a0, b2, accv[c][0][2]);
      accv[c][0][3] = fmaf(a0, b3, accv[c][0][3]);
      accv[c][1][0] = fmaf(a1, b0, accv[c][1][0]);
      accv[c][1][1] = fmaf(a1, b1, accv[c][1][1]);
      accv[c][1][2] = fmaf(a1, b2, accv[c][1][2]);
      accv[c][1][3] = fmaf(a1, b3, accv[c][1][3]);
    }
  }
  #pragma unroll
  for (int i = 0; i < 2; ++i) {
    #pragma unroll
    for (int j = 0; j < 4; ++j) {
      size_t base = (size_t)(n0 + tn * 2 + i) * 256 + 64 + (tw * 4 + j) * 3;
      out_[base + 0] += accv[0][i][j] * AGG_SCALE;
      out_[base + 1] += accv[1][i][j] * AGG_SCALE;
      out_[base + 2] += accv[2][i][j] * AGG_SCALE;
    }
  }
}

extern "C" void kernel_launch(void* const* d_in, const int* in_sizes, int n_in,
                              void* d_out, int out_size, void* d_ws, size_t ws_size,
                              hipStream_t stream) {
  const float* node_feat  = (const float*)d_in[0];
  const float* node_attr  = (const float*)d_in[1];
  const float* edge_sh    = (const float*)d_in[2];
  const float* edge_basis = (const float*)d_in[3];
  const float* W1s        = (const float*)d_in[4];
  const float* W1v        = (const float*)d_in[5];
  const float* Wfc1       = (const float*)d_in[6];
  const float* Wfc2       = (const float*)d_in[7];
  const float* W2s        = (const float*)d_in[8];
  const float* W2v        = (const float*)d_in[9];
  const float* Wsc_s      = (const float*)d_in[10];
  const float* Wsc_v      = (const float*)d_in[11];
  const int*   edge_idx   = (const int*)d_in[12];
  float* out = (float*)d_out;

  char* ws = (char*)d_ws;
  float* ws_s   = (float*)ws;                                  // N*64 f
  float* ws_v   = (float*)(ws + (size_t)NN * 64 * 4);          // N*192 f
  float* aggS   = (float*)(ws + (size_t)NN * 256 * 4);         // N*128 f
  float* aggV   = (float*)(ws + (size_t)NN * 384 * 4);         // N*384 f
  int*   deg    = (int*)  (ws + (size_t)NN * 768 * 4);         // N int
  int*   cursor = (int*)  (ws + (size_t)NN * 769 * 4);         // N int
  int*   csr    = (int*)  (ws + (size_t)NN * 770 * 4);         // E int

  hipMemsetAsync(aggS, 0, (size_t)NN * 512 * sizeof(float), stream);
  hipMemsetAsync(deg, 0, (size_t)NN * sizeof(int), stream);

  k_hist   <<<EE / 256, 256, 0, stream>>>(edge_idx, deg);
  k_scan   <<<1, 1024, 0, stream>>>(deg, cursor);
  k_scatter<<<EE / 256, 256, 0, stream>>>(edge_idx, cursor, csr);

  k1_node_prep<<<NN / 32, 256, 0, stream>>>(node_feat, node_attr, W1s, W1v,
                                            Wsc_s, Wsc_v, out, ws_s, ws_v);
  k2_edge_csr <<<EE / 32, 256, 0, stream>>>(edge_sh, edge_basis, Wfc1, Wfc2,
                                            edge_idx, csr, ws_s, ws_v, aggS, aggV);
  k4_final    <<<NN / 32, 256, 0, stream>>>(aggS, aggV, W2s, W2v, out);
}

// Round 4
// 618.523 us; speedup vs baseline: 1.4696x; 1.0264x over previous
//
#include <hip/hip_runtime.h>
#include <math.h>

#define NN 20000
#define EE 320000

// scales
#define INV_UV    0.04419417382415922f   // 1/sqrt(64*8)
#define INV_MULS  0.125f                 // 1/sqrt(64)
#define S_BASIS   0.35355339059327373f   // 1/sqrt(8)
#define S_HID     0.125f                 // 1/sqrt(64)
#define INV_SQ3   0.5773502691896258f
#define AGG_SCALE (0.25f * 0.08838834764831845f)  // inv_nn * inv_mid

typedef __attribute__((ext_vector_type(8))) short bf16x8;
typedef __attribute__((ext_vector_type(4))) float f32x4;

__device__ __forceinline__ float sspf(float x) {
  return fmaxf(x, 0.0f) + __logf(1.0f + __expf(-fabsf(x))) - 0.69314718055994531f;
}

__device__ __forceinline__ short f2bf(float f) {
  unsigned u = __float_as_uint(f);
  u += 0x7fffu + ((u >> 16) & 1u);       // round-to-nearest-even
  return (short)(u >> 16);
}

// ---------------------------------------------------------------------------
// CSR build: histogram -> single-block scan -> scatter
// ---------------------------------------------------------------------------
__global__ __launch_bounds__(256) void k_hist(const int* __restrict__ edge_idx,
                                              int* __restrict__ deg) {
  int e = blockIdx.x * 256 + threadIdx.x;
  atomicAdd(&deg[edge_idx[2 * (size_t)e]], 1);
}

__global__ __launch_bounds__(1024) void k_scan(const int* __restrict__ deg,
                                               int* __restrict__ cursor) {
  __shared__ int part[1024];
  const int t = threadIdx.x;
  const int base = t * 20;
  int loc[20];
  int run = 0;
  #pragma unroll
  for (int i = 0; i < 20; ++i) {
    int idx = base + i;
    int v = (idx < NN) ? deg[idx] : 0;
    loc[i] = run; run += v;
  }
  part[t] = run;
  __syncthreads();
  for (int off = 1; off < 1024; off <<= 1) {
    int v = (t >= off) ? part[t - off] : 0;
    __syncthreads();
    part[t] += v;
    __syncthreads();
  }
  int ex = (t > 0) ? part[t - 1] : 0;
  #pragma unroll
  for (int i = 0; i < 20; ++i) {
    int idx = base + i;
    if (idx < NN) cursor[idx] = ex + loc[i];
  }
}

__global__ __launch_bounds__(256) void k_scatter(const int* __restrict__ edge_idx,
                                                 int* __restrict__ cursor,
                                                 int* __restrict__ csr) {
  int e = blockIdx.x * 256 + threadIdx.x;
  int dst = edge_idx[2 * (size_t)e];
  int pos = atomicAdd(&cursor[dst], 1);
  csr[pos] = e;
}

// ---------------------------------------------------------------------------
// K1: per-node prep (unchanged; ~76% of fp32 peak).
// ---------------------------------------------------------------------------
__global__ __launch_bounds__(256) void k1_node_prep(
    const float* __restrict__ node_feat, const float* __restrict__ node_attr,
    const float* __restrict__ W1s, const float* __restrict__ W1v,
    const float* __restrict__ Wsc_s, const float* __restrict__ Wsc_v,
    float* __restrict__ out_, float* __restrict__ ws_s, float* __restrict__ ws_v)
{
  __shared__ float s0T[64][33];
  __shared__ float v0T[3][64][33];
  __shared__ float attrT[8][33];
  __shared__ float XT[64][36];
  __shared__ float Wl[64][68];

  const int t = threadIdx.x;
  const int n0 = blockIdx.x * 32;

  #pragma unroll
  for (int i = 0; i < 32; ++i) {
    int idx = t + i * 256;
    int n = idx >> 8, j = idx & 255;
    float val = node_feat[(size_t)(n0 + n) * 256 + j];
    if (j < 64) s0T[j][n] = val;
    else { int r = j - 64; v0T[r % 3][r / 3][n] = val; }
  }
  {
    int n = t >> 3, v = t & 7;
    attrT[v][n] = node_attr[(size_t)(n0 + n) * 8 + v];
  }
  __syncthreads();

  const int tn = t >> 4;
  const int tw = t & 15;

  for (int ch = 0; ch < 4; ++ch) {
    const float (*S)[33] = (ch == 0) ? s0T : v0T[ch - 1];
    const float* Wg = (ch == 0) ? Wsc_s : Wsc_v;
    float acc[2][4] = {{0.f,0.f,0.f,0.f},{0.f,0.f,0.f,0.f}};
    for (int kc = 0; kc < 8; ++kc) {
      #pragma unroll
      for (int i = 0; i < 8; ++i) {
        int idx = t + i * 256;
        int kk = idx >> 5, n = idx & 31;
        XT[kk][n] = S[kc * 8 + (kk >> 3)][n] * attrT[kk & 7][n];
      }
      #pragma unroll
      for (int i = 0; i < 16; ++i) {
        int idx = t + i * 256;
        int kk = idx >> 6, w = idx & 63;
        Wl[kk][w] = Wg[(size_t)(kc * 64 + kk) * 64 + w];
      }
      __syncthreads();
      #pragma unroll 8
      for (int kk = 0; kk < 64; ++kk) {
        float a0 = XT[kk][tn * 2 + 0];
        float a1 = XT[kk][tn * 2 + 1];
        float b0 = Wl[kk][tw * 4 + 0];
        float b1 = Wl[kk][tw * 4 + 1];
        float b2 = Wl[kk][tw * 4 + 2];
        float b3 = Wl[kk][tw * 4 + 3];
        acc[0][0] = fmaf(a0, b0, acc[0][0]);
        acc[0][1] = fmaf(a0, b1, acc[0][1]);
        acc[0][2] = fmaf(a0, b2, acc[0][2]);
        acc[0][3] = fmaf(a0, b3, acc[0][3]);
        acc[1][0] = fmaf(a1, b0, acc[1][0]);
        acc[1][1] = fmaf(a1, b1, acc[1][1]);
        acc[1][2] = fmaf(a1, b2, acc[1][2]);
        acc[1][3] = fmaf(a1, b3, acc[1][3]);
      }
      __syncthreads();
    }
    #pragma unroll
    for (int i = 0; i < 2; ++i) {
      int n = n0 + tn * 2 + i;
      #pragma unroll
      for (int j = 0; j < 4; ++j) {
        int w = tw * 4 + j;
        float val = acc[i][j] * INV_UV;
        if (ch == 0) out_[(size_t)n * 256 + w] = val;
        else         out_[(size_t)n * 256 + 64 + w * 3 + (ch - 1)] = val;
      }
    }
  }

  {
    #pragma unroll
    for (int i = 0; i < 16; ++i) {
      int idx = t + i * 256;
      Wl[idx >> 6][idx & 63] = W1s[idx];
    }
    __syncthreads();
    float acc[2][4] = {{0.f,0.f,0.f,0.f},{0.f,0.f,0.f,0.f}};
    #pragma unroll 8
    for (int kk = 0; kk < 64; ++kk) {
      float a0 = s0T[kk][tn * 2 + 0];
      float a1 = s0T[kk][tn * 2 + 1];
      float b0 = Wl[kk][tw * 4 + 0];
      float b1 = Wl[kk][tw * 4 + 1];
      float b2 = Wl[kk][tw * 4 + 2];
      float b3 = Wl[kk][tw * 4 + 3];
      acc[0][0] = fmaf(a0, b0, acc[0][0]);
      acc[0][1] = fmaf(a0, b1, acc[0][1]);
      acc[0][2] = fmaf(a0, b2, acc[0][2]);
      acc[0][3] = fmaf(a0, b3, acc[0][3]);
      acc[1][0] = fmaf(a1, b0, acc[1][0]);
      acc[1][1] = fmaf(a1, b1, acc[1][1]);
      acc[1][2] = fmaf(a1, b2, acc[1][2]);
      acc[1][3] = fmaf(a1, b3, acc[1][3]);
    }
    #pragma unroll
    for (int i = 0; i < 2; ++i) {
      int n = n0 + tn * 2 + i;
      #pragma unroll
      for (int j = 0; j < 4; ++j)
        ws_s[(size_t)n * 64 + tw * 4 + j] = acc[i][j] * INV_MULS;
    }
    __syncthreads();
    #pragma unroll
    for (int i = 0; i < 16; ++i) {
      int idx = t + i * 256;
      Wl[idx >> 6][idx & 63] = W1v[idx];
    }
    __syncthreads();
    #pragma unroll 1
    for (int c = 0; c < 3; ++c) {
      float acc2[2][4] = {{0.f,0.f,0.f,0.f},{0.f,0.f,0.f,0.f}};
      #pragma unroll 8
      for (int kk = 0; kk < 64; ++kk) {
        float a0 = v0T[c][kk][tn * 2 + 0];
        float a1 = v0T[c][kk][tn * 2 + 1];
        float b0 = Wl[kk][tw * 4 + 0];
        float b1 = Wl[kk][tw * 4 + 1];
        float b2 = Wl[kk][tw * 4 + 2];
        float b3 = Wl[kk][tw * 4 + 3];
        acc2[0][0] = fmaf(a0, b0, acc2[0][0]);
        acc2[0][1] = fmaf(a0, b1, acc2[0][1]);
        acc2[0][2] = fmaf(a0, b2, acc2[0][2]);
        acc2[0][3] = fmaf(a0, b3, acc2[0][3]);
        acc2[1][0] = fmaf(a1, b0, acc2[1][0]);
        acc2[1][1] = fmaf(a1, b1, acc2[1][1]);
        acc2[1][2] = fmaf(a1, b2, acc2[1][2]);
        acc2[1][3] = fmaf(a1, b3, acc2[1][3]);
      }
      #pragma unroll
      for (int i = 0; i < 2; ++i) {
        int n = n0 + tn * 2 + i;
        #pragma unroll
        for (int j = 0; j < 4; ++j)
          ws_v[((size_t)n * 3 + c) * 64 + tw * 4 + j] = acc2[i][j] * INV_MULS;
      }
    }
  }
}

// ---------------------------------------------------------------------------
// K2 (CSR + MFMA): 32 dst-sorted edges / block, 4 waves.
//   MLP2 (H[32x64] @ Wfc2[64x256]) on matrix cores (bf16 in, fp32 acc).
//   Wave wv computes+consumes exactly columns [wv*64, wv*64+64) = its W-part.
//   TP accumulates in registers; flush by atomicAdd on dst change.
// Fragment layouts (mfma_f32_16x16x32_bf16, verified convention):
//   A: row=lane&15, k=(lane>>4)*8+j ; B: col=lane&15, same k
//   C/D: col=lane&15, row=(lane>>4)*4+reg
// ---------------------------------------------------------------------------
__global__ __launch_bounds__(256) void k2_edge_csr(
    const float* __restrict__ edge_sh, const float* __restrict__ edge_basis,
    const float* __restrict__ Wfc1, const float* __restrict__ Wfc2,
    const int* __restrict__ edge_idx, const int* __restrict__ csr,
    const float* __restrict__ ws_s, const float* __restrict__ ws_v,
    float* __restrict__ aggS, float* __restrict__ aggV)
{
  __shared__ float basisL[32][8];
  __shared__ float wfc1[8][64];
  __shared__ short Hlb[32 * 64];      // bf16 H, XOR-swizzled rows (4 KB)
  __shared__ float Wt[32][260];       // +4 pad: conflict-free MFMA-out stores
  __shared__ float shL[32][4];
  __shared__ int   srcL[32];
  __shared__ int   dstL[32];

  const int t = threadIdx.x;
  const int e0 = blockIdx.x * 32;
  const int wv = t >> 6, lane = t & 63;

  // ---- stage edge data ----
  {
    int eb = csr[e0 + (t >> 3)];
    basisL[t >> 3][t & 7] = edge_basis[(size_t)eb * 8 + (t & 7)];
  }
  if (t < 32) {
    int eid = csr[e0 + t];
    int2 di = *(const int2*)(edge_idx + 2 * (size_t)eid);
    dstL[t] = di.x; srcL[t] = di.y;
    float4 s4 = *(const float4*)(edge_sh + 4 * (size_t)eid);
    shL[t][0] = s4.x; shL[t][1] = s4.y; shL[t][2] = s4.z; shL[t][3] = s4.w;
  }
  #pragma unroll
  for (int i = 0; i < 2; ++i) {
    int idx = t + i * 256;
    wfc1[idx >> 6][idx & 63] = Wfc1[idx] * S_BASIS;
  }

  // ---- B fragments: Wfc2 cols [wv*64, wv*64+64), bf16, S_HID folded ----
  bf16x8 bfrag[2][4];
  {
    const int colb = wv * 64 + (lane & 15);
    const int krow = (lane >> 4) * 8;
    #pragma unroll
    for (int ks = 0; ks < 2; ++ks)
      #pragma unroll
      for (int nt = 0; nt < 4; ++nt)
        #pragma unroll
        for (int j = 0; j < 8; ++j) {
          float f = Wfc2[(size_t)(ks * 32 + krow + j) * 256 + colb + nt * 16];
          bfrag[ks][nt][j] = f2bf(f * S_HID);
        }
  }
  __syncthreads();

  // ---- H = ssp(basis @ wfc1) -> bf16 pairs into swizzled LDS ----
  #pragma unroll
  for (int i = 0; i < 4; ++i) {
    int idx = t + i * 256;
    int e = idx >> 5, j2 = idx & 31;
    float a0 = 0.f, a1 = 0.f;
    #pragma unroll
    for (int b = 0; b < 8; ++b) {
      float bs = basisL[e][b];
      a0 = fmaf(bs, wfc1[b][2 * j2 + 0], a0);
      a1 = fmaf(bs, wfc1[b][2 * j2 + 1], a1);
    }
    unsigned p = ((unsigned)(unsigned short)f2bf(sspf(a0))) |
                 (((unsigned)(unsigned short)f2bf(sspf(a1))) << 16);
    int byte_off = e * 128 + ((j2 * 4) ^ ((e & 7) << 4));
    *(unsigned*)((char*)Hlb + byte_off) = p;
  }
  __syncthreads();

  // ---- MFMA: Wt = H @ Wfc2 (wave wv -> cols wv*64..wv*64+63) ----
  {
    bf16x8 afrag[2][2];  // [mtile][kstep]
    const int er = lane & 15;
    const int kr = (lane >> 4) * 8;
    #pragma unroll
    for (int mt = 0; mt < 2; ++mt)
      #pragma unroll
      for (int ks = 0; ks < 2; ++ks) {
        int e = mt * 16 + er;
        int byte_off = e * 128 + (((ks * 32 + kr) * 2) ^ ((e & 7) << 4));
        afrag[mt][ks] = *(const bf16x8*)((const char*)Hlb + byte_off);
      }
    #pragma unroll
    for (int mt = 0; mt < 2; ++mt)
      #pragma unroll
      for (int nt = 0; nt < 4; ++nt) {
        f32x4 acc = {0.f, 0.f, 0.f, 0.f};
        acc = __builtin_amdgcn_mfma_f32_16x16x32_bf16(afrag[mt][0], bfrag[0][nt], acc, 0, 0, 0);
        acc = __builtin_amdgcn_mfma_f32_16x16x32_bf16(afrag[mt][1], bfrag[1][nt], acc, 0, 0, 0);
        int row = mt * 16 + (lane >> 4) * 4;
        int col = wv * 64 + nt * 16 + (lane & 15);
        #pragma unroll
        for (int r = 0; r < 4; ++r)
          Wt[row + r][col] = acc[r];
      }
  }
  __syncthreads();

  // ---- TP + register accumulate + flush on dst change ----
  const int part = wv;
  float acc0 = 0.f, acc1 = 0.f, acc2 = 0.f;
  int cur = dstL[0];

  auto flush = [&](int node) {
    size_t nb = (size_t)node;
    if (part == 0)      atomicAdd(&aggS[nb * 128 + lane], acc0);
    else if (part == 3) atomicAdd(&aggS[nb * 128 + 64 + lane], acc0);
    else if (part == 1) {
      atomicAdd(&aggV[nb * 384 +       lane], acc0);
      atomicAdd(&aggV[nb * 384 + 128 + lane], acc1);
      atomicAdd(&aggV[nb * 384 + 256 + lane], acc2);
    } else {
      atomicAdd(&aggV[nb * 384 +  64 + lane], acc0);
      atomicAdd(&aggV[nb * 384 + 192 + lane], acc1);
      atomicAdd(&aggV[nb * 384 + 320 + lane], acc2);
    }
  };

  // software-pipelined gathers (no big FMA body left to hide latency)
  float nw = Wt[0][part * 64 + lane];
  float nxs = 0.f, nxv0 = 0.f, nxv1 = 0.f, nxv2 = 0.f;
  {
    int s0i = srcL[0];
    if (part <= 1) nxs = ws_s[(size_t)s0i * 64 + lane];
    else {
      nxv0 = ws_v[((size_t)s0i * 3 + 0) * 64 + lane];
      nxv1 = ws_v[((size_t)s0i * 3 + 1) * 64 + lane];
      nxv2 = ws_v[((size_t)s0i * 3 + 2) * 64 + lane];
    }
  }

  #pragma unroll 2
  for (int e = 0; e < 32; ++e) {
    const float w = nw, xs = nxs, xv0 = nxv0, xv1 = nxv1, xv2 = nxv2;
    if (e < 31) {
      nw = Wt[e + 1][part * 64 + lane];
      int sn = srcL[e + 1];
      if (part <= 1) nxs = ws_s[(size_t)sn * 64 + lane];
      else {
        nxv0 = ws_v[((size_t)sn * 3 + 0) * 64 + lane];
        nxv1 = ws_v[((size_t)sn * 3 + 1) * 64 + lane];
        nxv2 = ws_v[((size_t)sn * 3 + 2) * 64 + lane];
      }
    }
    const int dstE = dstL[e];
    if (dstE != cur) {
      flush(cur);
      acc0 = acc1 = acc2 = 0.f;
      cur = dstE;
    }
    const float q0 = shL[e][0], q1 = shL[e][1], q2 = shL[e][2], q3 = shL[e][3];
    if (part == 0) {
      acc0 = fmaf(w * xs, q0, acc0);
    } else if (part == 1) {
      float wx = w * xs;
      acc0 = fmaf(wx, q1, acc0);
      acc1 = fmaf(wx, q2, acc1);
      acc2 = fmaf(wx, q3, acc2);
    } else if (part == 2) {
      float wq = w * q0;
      acc0 = fmaf(wq, xv0, acc0);
      acc1 = fmaf(wq, xv1, acc1);
      acc2 = fmaf(wq, xv2, acc2);
    } else {
      float d = xv0 * q1 + xv1 * q2 + xv2 * q3;
      acc0 = fmaf(w * INV_SQ3, d, acc0);
    }
  }
  flush(cur);
}

// ---------------------------------------------------------------------------
// K4: final linear as micro-tiled GEMM, 32 nodes / block, 2x4 register tile.
// ---------------------------------------------------------------------------
__global__ __launch_bounds__(256) void k4_final(
    const float* __restrict__ aggS, const float* __restrict__ aggV,
    const float* __restrict__ W2s, const float* __restrict__ W2v,
    float* __restrict__ out_)
{
  __shared__ float XT[128][33];
  __shared__ float Wl[128][68];
  const int t = threadIdx.x;
  const int n0 = blockIdx.x * 32;
  const int tn = t >> 4, tw = t & 15;

  #pragma unroll
  for (int i = 0; i < 32; ++i) { int idx = t + i * 256; Wl[idx >> 6][idx & 63] = W2s[idx]; }
  #pragma unroll
  for (int i = 0; i < 16; ++i) {
    int idx = t + i * 256;
    int n = idx >> 7, k = idx & 127;
    XT[k][n] = aggS[(size_t)(n0 + n) * 128 + k];
  }
  __syncthreads();
  float acc[2][4] = {{0.f,0.f,0.f,0.f},{0.f,0.f,0.f,0.f}};
  #pragma unroll 8
  for (int kk = 0; kk < 128; ++kk) {
    float a0 = XT[kk][tn * 2 + 0], a1 = XT[kk][tn * 2 + 1];
    float b0 = Wl[kk][tw * 4 + 0], b1 = Wl[kk][tw * 4 + 1];
    float b2 = Wl[kk][tw * 4 + 2], b3 = Wl[kk][tw * 4 + 3];
    acc[0][0] = fmaf(a0, b0, acc[0][0]);
    acc[0][1] = fmaf(a0, b1, acc[0][1]);
    acc[0][2] = fmaf(a0, b2, acc[0][2]);
    acc[0][3] = fmaf(a0, b3, acc[0][3]);
    acc[1][0] = fmaf(a1, b0, acc[1][0]);
    acc[1][1] = fmaf(a1, b1, acc[1][1]);
    acc[1][2] = fmaf(a1, b2, acc[1][2]);
    acc[1][3] = fmaf(a1, b3, acc[1][3]);
  }
  #pragma unroll
  for (int i = 0; i < 2; ++i)
    #pragma unroll
    for (int j = 0; j < 4; ++j)
      out_[(size_t)(n0 + tn * 2 + i) * 256 + tw * 4 + j] += acc[i][j] * AGG_SCALE;

  __syncthreads();
  #pragma unroll
  for (int i = 0; i < 32; ++i) { int idx = t + i * 256; Wl[idx >> 6][idx & 63] = W2v[idx]; }
  float accv[3][2][4];
  #pragma unroll
  for (int c = 0; c < 3; ++c) {
    __syncthreads();
    #pragma unroll
    for (int i = 0; i < 16; ++i) {
      int idx = t + i * 256;
      int n = idx >> 7, k = idx & 127;
      XT[k][n] = aggV[(size_t)(n0 + n) * 384 + c * 128 + k];
    }
    __syncthreads();
    #pragma unroll
    for (int i = 0; i < 2; ++i)
      #pragma unroll
      for (int j = 0; j < 4; ++j) accv[c][i][j] = 0.f;
    #pragma unroll 8
    for (int kk = 0; kk < 128; ++kk) {
      float a0 = XT[kk][tn * 2 + 0], a1 = XT[kk][tn * 2 + 1];
      float b0 = Wl[kk][tw * 4 + 0], b1 = Wl[kk][tw * 4 + 1];
      float b2 = Wl[kk][tw * 4 + 2], b3 = Wl[kk][tw * 4 + 3];
      accv[c][0][0] = fmaf(a0, b0, accv[c][0][0]);
      accv[c][0][1] = fmaf(a0, b1, accv[c][0][1]);
      accv[c][0][2] = fmaf(a0, b2, accv[c][0][2]);
      accv[c][0][3] = fmaf(a0, b3, accv[c][0][3]);
      accv[c][1][0] = fmaf(a1, b0, accv[c][1][0]);
      accv[c][1][1] = fmaf(a1, b1, accv[c][1][1]);
      accv[c][1][2] = fmaf(a1, b2, accv[c][1][2]);
      accv[c][1][3] = fmaf(a1, b3, accv[c][1][3]);
    }
  }
  #pragma unroll
  for (int i = 0; i < 2; ++i) {
    #pragma unroll
    for (int j = 0; j < 4; ++j) {
      size_t base = (size_t)(n0 + tn * 2 + i) * 256 + 64 + (tw * 4 + j) * 3;
      out_[base + 0] += accv[0][i][j] * AGG_SCALE;
      out_[base + 1] += accv[1][i][j] * AGG_SCALE;
      out_[base + 2] += accv[2][i][j] * AGG_SCALE;
    }
  }
}

extern "C" void kernel_launch(void* const* d_in, const int* in_sizes, int n_in,
                              void* d_out, int out_size, void* d_ws, size_t ws_size,
                              hipStream_t stream) {
  const float* node_feat  = (const float*)d_in[0];
  const float* node_attr  = (const float*)d_in[1];
  const float* edge_sh    = (const float*)d_in[2];
  const float* edge_basis = (const float*)d_in[3];
  const float* W1s        = (const float*)d_in[4];
  const float* W1v        = (const float*)d_in[5];
  const float* Wfc1       = (const float*)d_in[6];
  const float* Wfc2       = (const float*)d_in[7];
  const float* W2s        = (const float*)d_in[8];
  const float* W2v        = (const float*)d_in[9];
  const float* Wsc_s      = (const float*)d_in[10];
  const float* Wsc_v      = (const float*)d_in[11];
  const int*   edge_idx   = (const int*)d_in[12];
  float* out = (float*)d_out;

  char* ws = (char*)d_ws;
  float* ws_s   = (float*)ws;                                  // N*64 f
  float* ws_v   = (float*)(ws + (size_t)NN * 64 * 4);          // N*192 f
  float* aggS   = (float*)(ws + (size_t)NN * 256 * 4);         // N*128 f
  float* aggV   = (float*)(ws + (size_t)NN * 384 * 4);         // N*384 f
  int*   deg    = (int*)  (ws + (size_t)NN * 768 * 4);         // N int
  int*   cursor = (int*)  (ws + (size_t)NN * 769 * 4);         // N int
  int*   csr    = (int*)  (ws + (size_t)NN * 770 * 4);         // E int

  hipMemsetAsync(aggS, 0, (size_t)NN * 512 * sizeof(float), stream);
  hipMemsetAsync(deg, 0, (size_t)NN * sizeof(int), stream);

  k_hist   <<<EE / 256, 256, 0, stream>>>(edge_idx, deg);
  k_scan   <<<1, 1024, 0, stream>>>(deg, cursor);
  k_scatter<<<EE / 256, 256, 0, stream>>>(edge_idx, cursor, csr);

  k1_node_prep<<<NN / 32, 256, 0, stream>>>(node_feat, node_attr, W1s, W1v,
                                            Wsc_s, Wsc_v, out, ws_s, ws_v);
  k2_edge_csr <<<EE / 32, 256, 0, stream>>>(edge_sh, edge_basis, Wfc1, Wfc2,
                                            edge_idx, csr, ws_s, ws_v, aggS, aggV);
  k4_final    <<<NN / 32, 256, 0, stream>>>(aggS, aggV, W2s, W2v, out);
}

// Round 5
// 526.536 us; speedup vs baseline: 1.7263x; 1.1747x over previous
//
#include <hip/hip_runtime.h>
#include <math.h>

#define NN 20000
#define EE 320000

// scales
#define INV_UV    0.04419417382415922f   // 1/sqrt(64*8)
#define INV_MULS  0.125f                 // 1/sqrt(64)
#define S_BASIS   0.35355339059327373f   // 1/sqrt(8)
#define S_HID     0.125f                 // 1/sqrt(64)
#define INV_SQ3   0.5773502691896258f
#define AGG_SCALE (0.25f * 0.08838834764831845f)  // inv_nn * inv_mid

typedef __attribute__((ext_vector_type(8))) short bf16x8;
typedef __attribute__((ext_vector_type(4))) float f32x4;

__device__ __forceinline__ float sspf(float x) {
  return fmaxf(x, 0.0f) + __logf(1.0f + __expf(-fabsf(x))) - 0.69314718055994531f;
}

__device__ __forceinline__ short f2bf(float f) {
  unsigned u = __float_as_uint(f);
  u += 0x7fffu + ((u >> 16) & 1u);       // round-to-nearest-even
  return (short)(u >> 16);
}

// ---------------------------------------------------------------------------
// CSR build: histogram -> single-block scan -> scatter
// ---------------------------------------------------------------------------
__global__ __launch_bounds__(256) void k_hist(const int* __restrict__ edge_idx,
                                              int* __restrict__ deg) {
  int e = blockIdx.x * 256 + threadIdx.x;
  atomicAdd(&deg[edge_idx[2 * (size_t)e]], 1);
}

__global__ __launch_bounds__(1024) void k_scan(const int* __restrict__ deg,
                                               int* __restrict__ cursor) {
  __shared__ int part[1024];
  const int t = threadIdx.x;
  const int base = t * 20;
  int loc[20];
  int run = 0;
  #pragma unroll
  for (int i = 0; i < 20; ++i) {
    int idx = base + i;
    int v = (idx < NN) ? deg[idx] : 0;
    loc[i] = run; run += v;
  }
  part[t] = run;
  __syncthreads();
  for (int off = 1; off < 1024; off <<= 1) {
    int v = (t >= off) ? part[t - off] : 0;
    __syncthreads();
    part[t] += v;
    __syncthreads();
  }
  int ex = (t > 0) ? part[t - 1] : 0;
  #pragma unroll
  for (int i = 0; i < 20; ++i) {
    int idx = base + i;
    if (idx < NN) cursor[idx] = ex + loc[i];
  }
}

__global__ __launch_bounds__(256) void k_scatter(const int* __restrict__ edge_idx,
                                                 int* __restrict__ cursor,
                                                 int* __restrict__ csr) {
  int e = blockIdx.x * 256 + threadIdx.x;
  int dst = edge_idx[2 * (size_t)e];
  int pos = atomicAdd(&cursor[dst], 1);
  csr[pos] = e;
}

// ---------------------------------------------------------------------------
// K1: per-node prep (unchanged; ~76% of fp32 peak).
// ---------------------------------------------------------------------------
__global__ __launch_bounds__(256) void k1_node_prep(
    const float* __restrict__ node_feat, const float* __restrict__ node_attr,
    const float* __restrict__ W1s, const float* __restrict__ W1v,
    const float* __restrict__ Wsc_s, const float* __restrict__ Wsc_v,
    float* __restrict__ out_, float* __restrict__ ws_s, float* __restrict__ ws_v)
{
  __shared__ float s0T[64][33];
  __shared__ float v0T[3][64][33];
  __shared__ float attrT[8][33];
  __shared__ float XT[64][36];
  __shared__ float Wl[64][68];

  const int t = threadIdx.x;
  const int n0 = blockIdx.x * 32;

  #pragma unroll
  for (int i = 0; i < 32; ++i) {
    int idx = t + i * 256;
    int n = idx >> 8, j = idx & 255;
    float val = node_feat[(size_t)(n0 + n) * 256 + j];
    if (j < 64) s0T[j][n] = val;
    else { int r = j - 64; v0T[r % 3][r / 3][n] = val; }
  }
  {
    int n = t >> 3, v = t & 7;
    attrT[v][n] = node_attr[(size_t)(n0 + n) * 8 + v];
  }
  __syncthreads();

  const int tn = t >> 4;
  const int tw = t & 15;

  for (int ch = 0; ch < 4; ++ch) {
    const float (*S)[33] = (ch == 0) ? s0T : v0T[ch - 1];
    const float* Wg = (ch == 0) ? Wsc_s : Wsc_v;
    float acc[2][4] = {{0.f,0.f,0.f,0.f},{0.f,0.f,0.f,0.f}};
    for (int kc = 0; kc < 8; ++kc) {
      #pragma unroll
      for (int i = 0; i < 8; ++i) {
        int idx = t + i * 256;
        int kk = idx >> 5, n = idx & 31;
        XT[kk][n] = S[kc * 8 + (kk >> 3)][n] * attrT[kk & 7][n];
      }
      #pragma unroll
      for (int i = 0; i < 16; ++i) {
        int idx = t + i * 256;
        int kk = idx >> 6, w = idx & 63;
        Wl[kk][w] = Wg[(size_t)(kc * 64 + kk) * 64 + w];
      }
      __syncthreads();
      #pragma unroll 8
      for (int kk = 0; kk < 64; ++kk) {
        float a0 = XT[kk][tn * 2 + 0];
        float a1 = XT[kk][tn * 2 + 1];
        float b0 = Wl[kk][tw * 4 + 0];
        float b1 = Wl[kk][tw * 4 + 1];
        float b2 = Wl[kk][tw * 4 + 2];
        float b3 = Wl[kk][tw * 4 + 3];
        acc[0][0] = fmaf(a0, b0, acc[0][0]);
        acc[0][1] = fmaf(a0, b1, acc[0][1]);
        acc[0][2] = fmaf(a0, b2, acc[0][2]);
        acc[0][3] = fmaf(a0, b3, acc[0][3]);
        acc[1][0] = fmaf(a1, b0, acc[1][0]);
        acc[1][1] = fmaf(a1, b1, acc[1][1]);
        acc[1][2] = fmaf(a1, b2, acc[1][2]);
        acc[1][3] = fmaf(a1, b3, acc[1][3]);
      }
      __syncthreads();
    }
    #pragma unroll
    for (int i = 0; i < 2; ++i) {
      int n = n0 + tn * 2 + i;
      #pragma unroll
      for (int j = 0; j < 4; ++j) {
        int w = tw * 4 + j;
        float val = acc[i][j] * INV_UV;
        if (ch == 0) out_[(size_t)n * 256 + w] = val;
        else         out_[(size_t)n * 256 + 64 + w * 3 + (ch - 1)] = val;
      }
    }
  }

  {
    #pragma unroll
    for (int i = 0; i < 16; ++i) {
      int idx = t + i * 256;
      Wl[idx >> 6][idx & 63] = W1s[idx];
    }
    __syncthreads();
    float acc[2][4] = {{0.f,0.f,0.f,0.f},{0.f,0.f,0.f,0.f}};
    #pragma unroll 8
    for (int kk = 0; kk < 64; ++kk) {
      float a0 = s0T[kk][tn * 2 + 0];
      float a1 = s0T[kk][tn * 2 + 1];
      float b0 = Wl[kk][tw * 4 + 0];
      float b1 = Wl[kk][tw * 4 + 1];
      float b2 = Wl[kk][tw * 4 + 2];
      float b3 = Wl[kk][tw * 4 + 3];
      acc[0][0] = fmaf(a0, b0, acc[0][0]);
      acc[0][1] = fmaf(a0, b1, acc[0][1]);
      acc[0][2] = fmaf(a0, b2, acc[0][2]);
      acc[0][3] = fmaf(a0, b3, acc[0][3]);
      acc[1][0] = fmaf(a1, b0, acc[1][0]);
      acc[1][1] = fmaf(a1, b1, acc[1][1]);
      acc[1][2] = fmaf(a1, b2, acc[1][2]);
      acc[1][3] = fmaf(a1, b3, acc[1][3]);
    }
    #pragma unroll
    for (int i = 0; i < 2; ++i) {
      int n = n0 + tn * 2 + i;
      #pragma unroll
      for (int j = 0; j < 4; ++j)
        ws_s[(size_t)n * 64 + tw * 4 + j] = acc[i][j] * INV_MULS;
    }
    __syncthreads();
    #pragma unroll
    for (int i = 0; i < 16; ++i) {
      int idx = t + i * 256;
      Wl[idx >> 6][idx & 63] = W1v[idx];
    }
    __syncthreads();
    #pragma unroll 1
    for (int c = 0; c < 3; ++c) {
      float acc2[2][4] = {{0.f,0.f,0.f,0.f},{0.f,0.f,0.f,0.f}};
      #pragma unroll 8
      for (int kk = 0; kk < 64; ++kk) {
        float a0 = v0T[c][kk][tn * 2 + 0];
        float a1 = v0T[c][kk][tn * 2 + 1];
        float b0 = Wl[kk][tw * 4 + 0];
        float b1 = Wl[kk][tw * 4 + 1];
        float b2 = Wl[kk][tw * 4 + 2];
        float b3 = Wl[kk][tw * 4 + 3];
        acc2[0][0] = fmaf(a0, b0, acc2[0][0]);
        acc2[0][1] = fmaf(a0, b1, acc2[0][1]);
        acc2[0][2] = fmaf(a0, b2, acc2[0][2]);
        acc2[0][3] = fmaf(a0, b3, acc2[0][3]);
        acc2[1][0] = fmaf(a1, b0, acc2[1][0]);
        acc2[1][1] = fmaf(a1, b1, acc2[1][1]);
        acc2[1][2] = fmaf(a1, b2, acc2[1][2]);
        acc2[1][3] = fmaf(a1, b3, acc2[1][3]);
      }
      #pragma unroll
      for (int i = 0; i < 2; ++i) {
        int n = n0 + tn * 2 + i;
        #pragma unroll
        for (int j = 0; j < 4; ++j)
          ws_v[((size_t)n * 3 + c) * 64 + tw * 4 + j] = acc2[i][j] * INV_MULS;
      }
    }
  }
}

// ---------------------------------------------------------------------------
// K2 (CSR + MFMA + bulk-prefetched gathers): 32 dst-sorted edges / block.
//   Gather chunk 0 (16 edges) issued BEFORE H/MFMA phases (latency hidden
//   under ~1K cycles of compute); chunk 1 issued at TP start, hidden under
//   chunk-0 processing. TP loop fully unrolled -> gathers stay in VGPRs.
// ---------------------------------------------------------------------------
__global__ __launch_bounds__(256) void k2_edge_csr(
    const float* __restrict__ edge_sh, const float* __restrict__ edge_basis,
    const float* __restrict__ Wfc1, const float* __restrict__ Wfc2,
    const int* __restrict__ edge_idx, const int* __restrict__ csr,
    const float* __restrict__ ws_s, const float* __restrict__ ws_v,
    float* __restrict__ aggS, float* __restrict__ aggV)
{
  __shared__ float basisL[32][8];
  __shared__ float wfc1[8][64];
  __shared__ short Hlb[32 * 64];      // bf16 H, XOR-swizzled rows (4 KB)
  __shared__ float Wt[32][260];
  __shared__ float shL[32][4];
  __shared__ int   srcL[32];
  __shared__ int   dstL[32];

  const int t = threadIdx.x;
  const int e0 = blockIdx.x * 32;
  const int wv = t >> 6, lane = t & 63;

  // ---- stage edge data ----
  {
    int eb = csr[e0 + (t >> 3)];
    basisL[t >> 3][t & 7] = edge_basis[(size_t)eb * 8 + (t & 7)];
  }
  if (t < 32) {
    int eid = csr[e0 + t];
    int2 di = *(const int2*)(edge_idx + 2 * (size_t)eid);
    dstL[t] = di.x; srcL[t] = di.y;
    float4 s4 = *(const float4*)(edge_sh + 4 * (size_t)eid);
    shL[t][0] = s4.x; shL[t][1] = s4.y; shL[t][2] = s4.z; shL[t][3] = s4.w;
  }
  #pragma unroll
  for (int i = 0; i < 2; ++i) {
    int idx = t + i * 256;
    wfc1[idx >> 6][idx & 63] = Wfc1[idx] * S_BASIS;
  }

  // ---- B fragments: Wfc2 cols [wv*64, wv*64+64), bf16, S_HID folded ----
  bf16x8 bfrag[2][4];
  {
    const int colb = wv * 64 + (lane & 15);
    const int krow = (lane >> 4) * 8;
    #pragma unroll
    for (int ks = 0; ks < 2; ++ks)
      #pragma unroll
      for (int nt = 0; nt < 4; ++nt)
        #pragma unroll
        for (int j = 0; j < 8; ++j) {
          float f = Wfc2[(size_t)(ks * 32 + krow + j) * 256 + colb + nt * 16];
          bfrag[ks][nt][j] = f2bf(f * S_HID);
        }
  }
  __syncthreads();   // srcL/dstL/shL/basisL/wfc1 now visible

  // ---- issue gather chunk 0 (edges 0..15); in flight through H + MFMA ----
  float gxs[16], g0[16], g1[16], g2[16];
  if (wv <= 1) {
    #pragma unroll
    for (int i = 0; i < 16; ++i)
      gxs[i] = ws_s[(size_t)srcL[i] * 64 + lane];
  } else {
    #pragma unroll
    for (int i = 0; i < 16; ++i) {
      const float* p = ws_v + (size_t)srcL[i] * 192 + lane;
      g0[i] = p[0]; g1[i] = p[64]; g2[i] = p[128];
    }
  }

  // ---- H = ssp(basis @ wfc1) -> bf16 pairs into swizzled LDS ----
  #pragma unroll
  for (int i = 0; i < 4; ++i) {
    int idx = t + i * 256;
    int e = idx >> 5, j2 = idx & 31;
    float a0 = 0.f, a1 = 0.f;
    #pragma unroll
    for (int b = 0; b < 8; ++b) {
      float bs = basisL[e][b];
      a0 = fmaf(bs, wfc1[b][2 * j2 + 0], a0);
      a1 = fmaf(bs, wfc1[b][2 * j2 + 1], a1);
    }
    unsigned p = ((unsigned)(unsigned short)f2bf(sspf(a0))) |
                 (((unsigned)(unsigned short)f2bf(sspf(a1))) << 16);
    int byte_off = e * 128 + ((j2 * 4) ^ ((e & 7) << 4));
    *(unsigned*)((char*)Hlb + byte_off) = p;
  }
  __syncthreads();

  // ---- MFMA: Wt = H @ Wfc2 (wave wv -> cols wv*64..wv*64+63) ----
  {
    bf16x8 afrag[2][2];
    const int er = lane & 15;
    const int kr = (lane >> 4) * 8;
    #pragma unroll
    for (int mt = 0; mt < 2; ++mt)
      #pragma unroll
      for (int ks = 0; ks < 2; ++ks) {
        int e = mt * 16 + er;
        int byte_off = e * 128 + (((ks * 32 + kr) * 2) ^ ((e & 7) << 4));
        afrag[mt][ks] = *(const bf16x8*)((const char*)Hlb + byte_off);
      }
    #pragma unroll
    for (int mt = 0; mt < 2; ++mt)
      #pragma unroll
      for (int nt = 0; nt < 4; ++nt) {
        f32x4 acc = {0.f, 0.f, 0.f, 0.f};
        acc = __builtin_amdgcn_mfma_f32_16x16x32_bf16(afrag[mt][0], bfrag[0][nt], acc, 0, 0, 0);
        acc = __builtin_amdgcn_mfma_f32_16x16x32_bf16(afrag[mt][1], bfrag[1][nt], acc, 0, 0, 0);
        int row = mt * 16 + (lane >> 4) * 4;
        int col = wv * 64 + nt * 16 + (lane & 15);
        #pragma unroll
        for (int r = 0; r < 4; ++r)
          Wt[row + r][col] = acc[r];
      }
  }
  __syncthreads();

  // ---- TP, fully unrolled; register accumulate; flush on dst change ----
  const int part = wv;
  float acc0 = 0.f, acc1 = 0.f, acc2 = 0.f;
  int cur = dstL[0];

  if (part <= 1) {
    // issue chunk 1 (edges 16..31); hidden under chunk-0 processing
    float hxs[16];
    #pragma unroll
    for (int i = 0; i < 16; ++i)
      hxs[i] = ws_s[(size_t)srcL[16 + i] * 64 + lane];
    #pragma unroll
    for (int e = 0; e < 32; ++e) {
      const float xs = (e < 16) ? gxs[e] : hxs[e - 16];
      const int dstE = dstL[e];
      if (dstE != cur) {
        if (part == 0) atomicAdd(&aggS[(size_t)cur * 128 + lane], acc0);
        else {
          atomicAdd(&aggV[(size_t)cur * 384 +       lane], acc0);
          atomicAdd(&aggV[(size_t)cur * 384 + 128 + lane], acc1);
          atomicAdd(&aggV[(size_t)cur * 384 + 256 + lane], acc2);
        }
        acc0 = acc1 = acc2 = 0.f;
        cur = dstE;
      }
      const float w = Wt[e][part * 64 + lane];
      if (part == 0) {
        acc0 = fmaf(w * xs, shL[e][0], acc0);
      } else {
        const float wx = w * xs;
        acc0 = fmaf(wx, shL[e][1], acc0);
        acc1 = fmaf(wx, shL[e][2], acc1);
        acc2 = fmaf(wx, shL[e][3], acc2);
      }
    }
    if (part == 0) atomicAdd(&aggS[(size_t)cur * 128 + lane], acc0);
    else {
      atomicAdd(&aggV[(size_t)cur * 384 +       lane], acc0);
      atomicAdd(&aggV[(size_t)cur * 384 + 128 + lane], acc1);
      atomicAdd(&aggV[(size_t)cur * 384 + 256 + lane], acc2);
    }
  } else {
    float h0[16], h1[16], h2[16];
    #pragma unroll
    for (int i = 0; i < 16; ++i) {
      const float* p = ws_v + (size_t)srcL[16 + i] * 192 + lane;
      h0[i] = p[0]; h1[i] = p[64]; h2[i] = p[128];
    }
    #pragma unroll
    for (int e = 0; e < 32; ++e) {
      const float xv0 = (e < 16) ? g0[e] : h0[e - 16];
      const float xv1 = (e < 16) ? g1[e] : h1[e - 16];
      const float xv2 = (e < 16) ? g2[e] : h2[e - 16];
      const int dstE = dstL[e];
      if (dstE != cur) {
        if (part == 3) atomicAdd(&aggS[(size_t)cur * 128 + 64 + lane], acc0);
        else {
          atomicAdd(&aggV[(size_t)cur * 384 +  64 + lane], acc0);
          atomicAdd(&aggV[(size_t)cur * 384 + 192 + lane], acc1);
          atomicAdd(&aggV[(size_t)cur * 384 + 320 + lane], acc2);
        }
        acc0 = acc1 = acc2 = 0.f;
        cur = dstE;
      }
      const float w = Wt[e][part * 64 + lane];
      if (part == 2) {
        const float wq = w * shL[e][0];
        acc0 = fmaf(wq, xv0, acc0);
        acc1 = fmaf(wq, xv1, acc1);
        acc2 = fmaf(wq, xv2, acc2);
      } else {
        const float d = fmaf(xv0, shL[e][1], fmaf(xv1, shL[e][2], xv2 * shL[e][3]));
        acc0 = fmaf(w * INV_SQ3, d, acc0);
      }
    }
    if (part == 3) atomicAdd(&aggS[(size_t)cur * 128 + 64 + lane], acc0);
    else {
      atomicAdd(&aggV[(size_t)cur * 384 +  64 + lane], acc0);
      atomicAdd(&aggV[(size_t)cur * 384 + 192 + lane], acc1);
      atomicAdd(&aggV[(size_t)cur * 384 + 320 + lane], acc2);
    }
  }
}

// ---------------------------------------------------------------------------
// K4: final linear as micro-tiled GEMM, 32 nodes / block, 2x4 register tile.
// ---------------------------------------------------------------------------
__global__ __launch_bounds__(256) void k4_final(
    const float* __restrict__ aggS, const float* __restrict__ aggV,
    const float* __restrict__ W2s, const float* __restrict__ W2v,
    float* __restrict__ out_)
{
  __shared__ float XT[128][33];
  __shared__ float Wl[128][68];
  const int t = threadIdx.x;
  const int n0 = blockIdx.x * 32;
  const int tn = t >> 4, tw = t & 15;

  #pragma unroll
  for (int i = 0; i < 32; ++i) { int idx = t + i * 256; Wl[idx >> 6][idx & 63] = W2s[idx]; }
  #pragma unroll
  for (int i = 0; i < 16; ++i) {
    int idx = t + i * 256;
    int n = idx >> 7, k = idx & 127;
    XT[k][n] = aggS[(size_t)(n0 + n) * 128 + k];
  }
  __syncthreads();
  float acc[2][4] = {{0.f,0.f,0.f,0.f},{0.f,0.f,0.f,0.f}};
  #pragma unroll 8
  for (int kk = 0; kk < 128; ++kk) {
    float a0 = XT[kk][tn * 2 + 0], a1 = XT[kk][tn * 2 + 1];
    float b0 = Wl[kk][tw * 4 + 0], b1 = Wl[kk][tw * 4 + 1];
    float b2 = Wl[kk][tw * 4 + 2], b3 = Wl[kk][tw * 4 + 3];
    acc[0][0] = fmaf(a0, b0, acc[0][0]);
    acc[0][1] = fmaf(a0, b1, acc[0][1]);
    acc[0][2] = fmaf(a0, b2, acc[0][2]);
    acc[0][3] = fmaf(a0, b3, acc[0][3]);
    acc[1][0] = fmaf(a1, b0, acc[1][0]);
    acc[1][1] = fmaf(a1, b1, acc[1][1]);
    acc[1][2] = fmaf(a1, b2, acc[1][2]);
    acc[1][3] = fmaf(a1, b3, acc[1][3]);
  }
  #pragma unroll
  for (int i = 0; i < 2; ++i)
    #pragma unroll
    for (int j = 0; j < 4; ++j)
      out_[(size_t)(n0 + tn * 2 + i) * 256 + tw * 4 + j] += acc[i][j] * AGG_SCALE;

  __syncthreads();
  #pragma unroll
  for (int i = 0; i < 32; ++i) { int idx = t + i * 256; Wl[idx >> 6][idx & 63] = W2v[idx]; }
  float accv[3][2][4];
  #pragma unroll
  for (int c = 0; c < 3; ++c) {
    __syncthreads();
    #pragma unroll
    for (int i = 0; i < 16; ++i) {
      int idx = t + i * 256;
      int n = idx >> 7, k = idx & 127;
      XT[k][n] = aggV[(size_t)(n0 + n) * 384 + c * 128 + k];
    }
    __syncthreads();
    #pragma unroll
    for (int i = 0; i < 2; ++i)
      #pragma unroll
      for (int j = 0; j < 4; ++j) accv[c][i][j] = 0.f;
    #pragma unroll 8
    for (int kk = 0; kk < 128; ++kk) {
      float a0 = XT[kk][tn * 2 + 0], a1 = XT[kk][tn * 2 + 1];
      float b0 = Wl[kk][tw * 4 + 0], b1 = Wl[kk][tw * 4 + 1];
      float b2 = Wl[kk][tw * 4 + 2], b3 = Wl[kk][tw * 4 + 3];
      accv[c][0][0] = fmaf(a0, b0, accv[c][0][0]);
      accv[c][0][1] = fmaf(a0, b1, accv[c][0][1]);
      accv[c][0][2] = fmaf(a0, b2, accv[c][0][2]);
      accv[c][0][3] = fmaf(a0, b3, accv[c][0][3]);
      accv[c][1][0] = fmaf(a1, b0, accv[c][1][0]);
      accv[c][1][1] = fmaf(a1, b1, accv[c][1][1]);
      accv[c][1][2] = fmaf(a1, b2, accv[c][1][2]);
      accv[c][1][3] = fmaf(a1, b3, accv[c][1][3]);
    }
  }
  #pragma unroll
  for (int i = 0; i < 2; ++i) {
    #pragma unroll
    for (int j = 0; j < 4; ++j) {
      size_t base = (size_t)(n0 + tn * 2 + i) * 256 + 64 + (tw * 4 + j) * 3;
      out_[base + 0] += accv[0][i][j] * AGG_SCALE;
      out_[base + 1] += accv[1][i][j] * AGG_SCALE;
      out_[base + 2] += accv[2][i][j] * AGG_SCALE;
    }
  }
}

extern "C" void kernel_launch(void* const* d_in, const int* in_sizes, int n_in,
                              void* d_out, int out_size, void* d_ws, size_t ws_size,
                              hipStream_t stream) {
  const float* node_feat  = (const float*)d_in[0];
  const float* node_attr  = (const float*)d_in[1];
  const float* edge_sh    = (const float*)d_in[2];
  const float* edge_basis = (const float*)d_in[3];
  const float* W1s        = (const float*)d_in[4];
  const float* W1v        = (const float*)d_in[5];
  const float* Wfc1       = (const float*)d_in[6];
  const float* Wfc2       = (const float*)d_in[7];
  const float* W2s        = (const float*)d_in[8];
  const float* W2v        = (const float*)d_in[9];
  const float* Wsc_s      = (const float*)d_in[10];
  const float* Wsc_v      = (const float*)d_in[11];
  const int*   edge_idx   = (const int*)d_in[12];
  float* out = (float*)d_out;

  char* ws = (char*)d_ws;
  float* ws_s   = (float*)ws;                                  // N*64 f
  float* ws_v   = (float*)(ws + (size_t)NN * 64 * 4);          // N*192 f
  float* aggS   = (float*)(ws + (size_t)NN * 256 * 4);         // N*128 f
  float* aggV   = (float*)(ws + (size_t)NN * 384 * 4);         // N*384 f
  int*   deg    = (int*)  (ws + (size_t)NN * 768 * 4);         // N int
  int*   cursor = (int*)  (ws + (size_t)NN * 769 * 4);         // N int
  int*   csr    = (int*)  (ws + (size_t)NN * 770 * 4);         // E int

  hipMemsetAsync(aggS, 0, (size_t)NN * 512 * sizeof(float), stream);
  hipMemsetAsync(deg, 0, (size_t)NN * sizeof(int), stream);

  k_hist   <<<EE / 256, 256, 0, stream>>>(edge_idx, deg);
  k_scan   <<<1, 1024, 0, stream>>>(deg, cursor);
  k_scatter<<<EE / 256, 256, 0, stream>>>(edge_idx, cursor, csr);

  k1_node_prep<<<NN / 32, 256, 0, stream>>>(node_feat, node_attr, W1s, W1v,
                                            Wsc_s, Wsc_v, out, ws_s, ws_v);
  k2_edge_csr <<<EE / 32, 256, 0, stream>>>(edge_sh, edge_basis, Wfc1, Wfc2,
                                            edge_idx, csr, ws_s, ws_v, aggS, aggV);
  k4_final    <<<NN / 32, 256, 0, stream>>>(aggS, aggV, W2s, W2v, out);
}